// Round 10
// baseline (338.773 us; speedup 1.0000x reference)
//
#include <hip/hip_runtime.h>
#include <hip/hip_bf16.h>

// R15: (1) tconv_all tiles widened to 128x64 (dst rows 256B, 64B/thread
//      contiguous stores) -- fixes tconv's 128B-scatter write bound (66us @
//      2.2TB/s). (2) out_gemm epilogue LDS-bounced to coalesced float4
//      stores (was 64MB of scalar 4B stores at 64B stride). All else = R14.
#define BB      4
#define SEQ     4096
#define DMODEL  1024
#define NHEAD   16
#define DK      64
#define LK      256
#define BH      (BB*NHEAD)   // 64
#define SPLITK  4

typedef unsigned short u16;
typedef unsigned int   u32;
typedef float f32x4  __attribute__((ext_vector_type(4)));
typedef _Float16 f16x8 __attribute__((ext_vector_type(8)));

__device__ __forceinline__ u16 f2h(float f) {
    _Float16 h = (_Float16)f;                 // v_cvt_f16_f32, RNE
    u16 r; __builtin_memcpy(&r, &h, 2); return r;
}
__device__ __forceinline__ u32 packh(float a, float b) {
    return (u32)f2h(a) | ((u32)f2h(b) << 16);
}
__device__ __forceinline__ f16x8 pack8h(float4 a, float4 b) {
    union { uint4 u; f16x8 h; } r;
    r.u = make_uint4(packh(a.x, a.y), packh(a.z, a.w),
                     packh(b.x, b.y), packh(b.z, b.w));
    return r.h;
}
// async global->LDS, 16B per lane (dest must be wave-uniform base + lane*16)
__device__ __forceinline__ void gl2lds16(const void* g, void* l) {
    __builtin_amdgcn_global_load_lds(
        (const __attribute__((address_space(1))) unsigned int*)g,
        (__attribute__((address_space(3))) unsigned int*)l,
        16, 0, 0);
}

// ---------------------------------------------------------------------------
// tconv body (proven, 64x64): f32 [R][C] tile -> f16 [C][R] tile. (fallbacks)
// ---------------------------------------------------------------------------
__device__ __forceinline__ void tconv_body(
    const float* __restrict__ S, u16* __restrict__ D,
    int ss, int ds, int r0, int c0, int t)
{
    __shared__ float T[64][65];
    {
        int rr = (t >> 4) * 4;
        int cc = (t & 15) * 4;
#pragma unroll
        for (int i = 0; i < 4; ++i) {
            float4 v = *(const float4*)(S + (size_t)(r0 + rr + i) * ss + c0 + cc);
            T[rr + i][cc + 0] = v.x; T[rr + i][cc + 1] = v.y;
            T[rr + i][cc + 2] = v.z; T[rr + i][cc + 3] = v.w;
        }
    }
    __syncthreads();
    int cr = t >> 2, rc = (t & 3) * 16;
    u32 o[8];
#pragma unroll
    for (int j = 0; j < 8; ++j)
        o[j] = packh(T[rc + 2 * j][cr], T[rc + 2 * j + 1][cr]);
    u16* d = D + (size_t)(c0 + cr) * ds + r0 + rc;
    *(uint4*)(d)     = make_uint4(o[0], o[1], o[2], o[3]);
    *(uint4*)(d + 8) = make_uint4(o[4], o[5], o[6], o[7]);
}

__global__ __launch_bounds__(256) void tconv(
    const float* __restrict__ src, u16* __restrict__ dst,
    int ss, int ds, size_t sbo, size_t dbo)
{
    tconv_body(src + (size_t)blockIdx.z * sbo, dst + (size_t)blockIdx.z * dbo,
               ss, ds, blockIdx.x * 64, blockIdx.y * 64, threadIdx.x);
}

__global__ __launch_bounds__(256) void wo_convert(
    const float* __restrict__ Wo, u16* __restrict__ WoT)
{
    tconv_body(Wo, WoT, DMODEL, DMODEL, blockIdx.y * 64, blockIdx.x * 64, threadIdx.x);
}

// ---------------------------------------------------------------------------
// tconv_body128 (R15): f32 [128 rows][64 cols] tile -> f16 [64][128] tile.
// dst rows are 256B; each thread stores 64B contiguous (4x uint4).
// ---------------------------------------------------------------------------
__device__ __forceinline__ void tconv_body128(
    const float* __restrict__ S, u16* __restrict__ D,
    int ss, int ds, int r0, int c0, int t)
{
    __shared__ float T[128][72];
    {
        int rr = t >> 4;             // +16 per iter
        int cc = (t & 15) * 4;
#pragma unroll
        for (int i = 0; i < 8; ++i) {
            float4 v = *(const float4*)(S + (size_t)(r0 + rr + i * 16) * ss + c0 + cc);
            float* dst = &T[rr + i * 16][cc];
            dst[0] = v.x; dst[1] = v.y; dst[2] = v.z; dst[3] = v.w;
        }
    }
    __syncthreads();
    int cr = t >> 2, rc = (t & 3) * 32;   // dst row cr, dst cols rc..rc+31
    u32 o[16];
#pragma unroll
    for (int j = 0; j < 16; ++j)
        o[j] = packh(T[rc + 2 * j][cr], T[rc + 2 * j + 1][cr]);
    u16* d = D + (size_t)(c0 + cr) * ds + r0 + rc;
    *(uint4*)(d)      = make_uint4(o[0],  o[1],  o[2],  o[3]);
    *(uint4*)(d + 8)  = make_uint4(o[4],  o[5],  o[6],  o[7]);
    *(uint4*)(d + 16) = make_uint4(o[8],  o[9],  o[10], o[11]);
    *(uint4*)(d + 24) = make_uint4(o[12], o[13], o[14], o[15]);
}

// ---------------------------------------------------------------------------
// tconv_all (R15, 128x64 tiles): all 5 prep transposes, 4480 blocks:
//  [0,128)     We | [128,256) Wf | [256,2304) K | [2304,4352) V | [4352,4480) Wo
// ---------------------------------------------------------------------------
__global__ __launch_bounds__(256) void tconv_all(
    const float* __restrict__ We, const float* __restrict__ Wf,
    const float* __restrict__ K,  const float* __restrict__ V,
    const float* __restrict__ Wo,
    u16* __restrict__ WeT, u16* __restrict__ WfT,
    u16* __restrict__ KT,  u16* __restrict__ VT, u16* __restrict__ WoT)
{
    const int id = blockIdx.x;
    const float* S; u16* D; int ss, ds, r0, c0;
    if (id < 256) {                       // We / Wf : [4096][256], 32x4 tiles
        int j = id & 127;
        S  = (id < 128) ? We : Wf;
        D  = (id < 128) ? WeT : WfT;
        ss = LK; ds = SEQ;
        r0 = (j & 31) * 128; c0 = (j >> 5) * 64;
    } else if (id < 4352) {               // K / V : [4096][1024] per b, 32x16 tiles
        int j  = id - 256;
        int isV = j >= 2048; if (isV) j -= 2048;
        int bz = j >> 9, rem = j & 511;
        S  = (isV ? V : K) + (size_t)bz * SEQ * DMODEL;
        D  = (isV ? VT : KT) + (size_t)bz * DMODEL * SEQ;
        ss = DMODEL; ds = SEQ;
        r0 = (rem & 31) * 128; c0 = (rem >> 5) * 64;
    } else {                              // Wo : [1024][1024], 8x16 tiles
        int j = id - 4352;
        S = Wo; D = WoT; ss = DMODEL; ds = DMODEL;
        r0 = (j & 7) * 128; c0 = (j >> 3) * 64;
    }
    tconv_body128(S, D, ss, ds, r0, c0, threadIdx.x);
}

// ---------------------------------------------------------------------------
// proj_gemm / proj_both (R11/R12-proven, fallback paths): batched TN GEMM.
// ---------------------------------------------------------------------------
#define PROJ_BODY(Ab, Bb, bias, Cb, bias_on_row, c_row_stride, c0, r0)          \
    const int t  = threadIdx.x;                                                 \
    const int lane = t & 63;                                                    \
    const int w  = t >> 6;                                                      \
    const int wr = w >> 1, wc = w & 1;                                          \
    const int q  = lane >> 4, c = lane & 15;                                    \
    __shared__ u16 As[2][128 * 64];                                             \
    __shared__ u16 Bs[2][128 * 64];                                             \
    auto stage = [&](int buf, int kk) {                                         \
        _Pragma("unroll")                                                       \
        for (int i = 0; i < 4; ++i) {                                           \
            int li  = i * 256 + t;                                              \
            int row = li >> 3;                                                  \
            int c8  = (li & 7) ^ (row & 7);                                     \
            gl2lds16(Ab + (size_t)(r0 + row) * SEQ + kk + c8 * 8, &As[buf][(size_t)li * 8]); \
            gl2lds16(Bb + (size_t)(c0 + row) * SEQ + kk + c8 * 8, &Bs[buf][(size_t)li * 8]); \
        }                                                                       \
    };                                                                          \
    f32x4 acc[4][4];                                                            \
    _Pragma("unroll")                                                           \
    for (int m = 0; m < 4; ++m)                                                 \
        _Pragma("unroll")                                                       \
        for (int n = 0; n < 4; ++n) acc[m][n] = (f32x4){0.f, 0.f, 0.f, 0.f};    \
    stage(0, 0);                                                                \
    __syncthreads();                                                            \
    int cur = 0;                                                                \
    for (int k0 = 0; k0 < SEQ; k0 += 64) {                                      \
        if (k0 + 64 < SEQ) stage(cur ^ 1, k0 + 64);                             \
        _Pragma("unroll")                                                       \
        for (int s = 0; s < 2; ++s) {                                           \
            f16x8 af[4], bf[4];                                                 \
            _Pragma("unroll")                                                   \
            for (int m = 0; m < 4; ++m) {                                       \
                int row = wr * 64 + m * 16 + c;                                 \
                int c8  = (s * 4 + q) ^ (row & 7);                              \
                af[m] = *(const f16x8*)&As[cur][row * 64 + c8 * 8];             \
            }                                                                   \
            _Pragma("unroll")                                                   \
            for (int n = 0; n < 4; ++n) {                                       \
                int row = wc * 64 + n * 16 + c;                                 \
                int c8  = (s * 4 + q) ^ (row & 7);                              \
                bf[n] = *(const f16x8*)&Bs[cur][row * 64 + c8 * 8];             \
            }                                                                   \
            _Pragma("unroll")                                                   \
            for (int m = 0; m < 4; ++m)                                         \
                _Pragma("unroll")                                               \
                for (int n = 0; n < 4; ++n)                                     \
                    acc[m][n] = __builtin_amdgcn_mfma_f32_16x16x32_f16(af[m], bf[n], acc[m][n], 0, 0, 0); \
        }                                                                       \
        __syncthreads();                                                        \
        cur ^= 1;                                                               \
    }                                                                           \
    if (bias_on_row) {                                                          \
        _Pragma("unroll")                                                       \
        for (int m = 0; m < 4; ++m) {                                           \
            int rowb = r0 + wr * 64 + m * 16 + q * 4;                           \
            _Pragma("unroll")                                                   \
            for (int r = 0; r < 4; ++r) {                                       \
                float bv = bias[rowb + r];                                      \
                u16* dst = Cb + (size_t)(rowb + r) * c_row_stride + c0 + wc * 64 + c; \
                _Pragma("unroll")                                               \
                for (int n = 0; n < 4; ++n) dst[n * 16] = f2h(acc[m][n][r] + bv); \
            }                                                                   \
        }                                                                       \
    } else {                                                                    \
        float bv[4];                                                            \
        _Pragma("unroll")                                                       \
        for (int n = 0; n < 4; ++n) bv[n] = bias[c0 + wc * 64 + n * 16 + c];    \
        _Pragma("unroll")                                                       \
        for (int m = 0; m < 4; ++m) {                                           \
            int rowb = r0 + wr * 64 + m * 16 + q * 4;                           \
            _Pragma("unroll")                                                   \
            for (int r = 0; r < 4; ++r) {                                       \
                u16* dst = Cb + (size_t)(rowb + r) * c_row_stride + c0 + wc * 64 + c; \
                _Pragma("unroll")                                               \
                for (int n = 0; n < 4; ++n) dst[n * 16] = f2h(acc[m][n][r] + bv[n]); \
            }                                                                   \
        }                                                                       \
    }

__global__ __launch_bounds__(256) void proj_gemm(
    const u16* __restrict__ A, const u16* __restrict__ B,
    const float* __restrict__ bias, u16* __restrict__ Cout,
    int bias_on_row, size_t a_batch, size_t b_batch,
    int c_row_stride, size_t c_batch)
{
    const u16* Ab = A + (size_t)blockIdx.z * a_batch;
    const u16* Bb = B + (size_t)blockIdx.z * b_batch;
    u16* Cb       = Cout + (size_t)blockIdx.z * c_batch;
    const int c0 = blockIdx.x * 128;
    const int r0 = blockIdx.y * 128;
    PROJ_BODY(Ab, Bb, bias, Cb, bias_on_row, c_row_stride, c0, r0)
}

__global__ __launch_bounds__(256) void proj_both(
    const u16* __restrict__ WeT, const u16* __restrict__ WfT,
    const u16* __restrict__ KT,  const u16* __restrict__ VT,
    const float* __restrict__ be, const float* __restrict__ bfp,
    u16* __restrict__ KpF, u16* __restrict__ VpF)
{
    const int id = blockIdx.x;
    const u16 *Ab, *Bb; const float* bias; u16* Cb;
    int bias_on_row, c_row_stride, c0, r0;
    if (id < 64) {              // K-proj: C[lk][dm] = WeT @ KT[b]^T + be[lk]
        int b = id >> 4, s = id & 15;
        c0 = (s & 7) * 128; r0 = (s >> 3) * 128;
        Ab = WeT; Bb = KT + (size_t)b * DMODEL * SEQ;
        bias = be; bias_on_row = 1;
        Cb = KpF + (size_t)b * LK * DMODEL; c_row_stride = DMODEL;
    } else {                    // V-proj: C[dm][lk] = VT[b] @ WfT^T + bf[lk]
        int j = id - 64, b = j >> 4, s = j & 15;
        c0 = (s & 1) * 128; r0 = (s >> 1) * 128;
        Ab = VT + (size_t)b * DMODEL * SEQ; Bb = WfT;
        bias = bfp; bias_on_row = 0;
        Cb = VpF + (size_t)b * DMODEL * LK; c_row_stride = LK;
    }
    PROJ_BODY(Ab, Bb, bias, Cb, bias_on_row, c_row_stride, c0, r0)
}

// ---------------------------------------------------------------------------
// proj_split (R14-proven): split-K, f32 partials (no bias).
// ---------------------------------------------------------------------------
__global__ __launch_bounds__(256) void proj_split(
    const u16* __restrict__ WeT, const u16* __restrict__ WfT,
    const u16* __restrict__ KT,  const u16* __restrict__ VT,
    float* __restrict__ PPK, float* __restrict__ PPV)
{
    const int sk = blockIdx.x >> 7;
    const int id = blockIdx.x & 127;
    const u16 *Ab, *Bb; float* Pout;
    int crs, c0, r0;
    if (id < 64) {              // K-proj partial [sk][b][lk][dm]
        int b = id >> 4, s = id & 15;
        c0 = (s & 7) * 128; r0 = (s >> 3) * 128;
        Ab = WeT; Bb = KT + (size_t)b * DMODEL * SEQ;
        Pout = PPK + ((size_t)sk * BB + b) * (LK * DMODEL); crs = DMODEL;
    } else {                    // V-proj partial [sk][b][dm][lk]
        int j = id - 64, b = j >> 4, s = j & 15;
        c0 = (s & 1) * 128; r0 = (s >> 1) * 128;
        Ab = VT + (size_t)b * DMODEL * SEQ; Bb = WfT;
        Pout = PPV + ((size_t)sk * BB + b) * (DMODEL * LK); crs = LK;
    }
    const int kbeg = sk * (SEQ / SPLITK), kend = kbeg + SEQ / SPLITK;

    const int t  = threadIdx.x;
    const int lane = t & 63;
    const int w  = t >> 6;
    const int wr = w >> 1, wc = w & 1;
    const int q  = lane >> 4, c = lane & 15;
    __shared__ u16 As[2][128 * 64];
    __shared__ u16 Bs[2][128 * 64];
    auto stage = [&](int buf, int kk) {
#pragma unroll
        for (int i = 0; i < 4; ++i) {
            int li  = i * 256 + t;
            int row = li >> 3;
            int c8  = (li & 7) ^ (row & 7);
            gl2lds16(Ab + (size_t)(r0 + row) * SEQ + kk + c8 * 8, &As[buf][(size_t)li * 8]);
            gl2lds16(Bb + (size_t)(c0 + row) * SEQ + kk + c8 * 8, &Bs[buf][(size_t)li * 8]);
        }
    };
    f32x4 acc[4][4];
#pragma unroll
    for (int m = 0; m < 4; ++m)
#pragma unroll
        for (int n = 0; n < 4; ++n) acc[m][n] = (f32x4){0.f, 0.f, 0.f, 0.f};
    stage(0, kbeg);
    __syncthreads();
    int cur = 0;
    for (int k0 = kbeg; k0 < kend; k0 += 64) {
        if (k0 + 64 < kend) stage(cur ^ 1, k0 + 64);
#pragma unroll
        for (int s = 0; s < 2; ++s) {
            f16x8 af[4], bf[4];
#pragma unroll
            for (int m = 0; m < 4; ++m) {
                int row = wr * 64 + m * 16 + c;
                int c8  = (s * 4 + q) ^ (row & 7);
                af[m] = *(const f16x8*)&As[cur][row * 64 + c8 * 8];
            }
#pragma unroll
            for (int n = 0; n < 4; ++n) {
                int row = wc * 64 + n * 16 + c;
                int c8  = (s * 4 + q) ^ (row & 7);
                bf[n] = *(const f16x8*)&Bs[cur][row * 64 + c8 * 8];
            }
#pragma unroll
            for (int m = 0; m < 4; ++m)
#pragma unroll
                for (int n = 0; n < 4; ++n)
                    acc[m][n] = __builtin_amdgcn_mfma_f32_16x16x32_f16(af[m], bf[n], acc[m][n], 0, 0, 0);
        }
        __syncthreads();
        cur ^= 1;
    }
#pragma unroll
    for (int m = 0; m < 4; ++m) {
        int rowb = r0 + wr * 64 + m * 16 + q * 4;
#pragma unroll
        for (int r = 0; r < 4; ++r) {
            float* dst = Pout + (size_t)(rowb + r) * crs + c0 + wc * 64 + c;
#pragma unroll
            for (int n = 0; n < 4; ++n) dst[n * 16] = acc[m][n][r];
        }
    }
}

// ---------------------------------------------------------------------------
// proj_reduce (R14-proven): sum SPLITK f32 partials + bias -> f16.
// ---------------------------------------------------------------------------
__global__ __launch_bounds__(256) void proj_reduce(
    const float* __restrict__ PPK, const float* __restrict__ PPV,
    const float* __restrict__ be,  const float* __restrict__ bfp,
    u16* __restrict__ KpF, u16* __restrict__ VpF)
{
    const int isV = blockIdx.y;
    const float* P    = isV ? PPV : PPK;
    const float* bias = isV ? bfp : be;
    u16* Out          = isV ? VpF : KpF;
    const size_t flat = ((size_t)blockIdx.x * 256 + threadIdx.x) * 4;  // elem idx
    const size_t skstride = (size_t)BB * LK * DMODEL;                  // floats
    float4 a = *(const float4*)(P + flat);
#pragma unroll
    for (int sk = 1; sk < SPLITK; ++sk) {
        float4 p = *(const float4*)(P + (size_t)sk * skstride + flat);
        a.x += p.x; a.y += p.y; a.z += p.z; a.w += p.w;
    }
    if (!isV) {
        float bv = bias[(flat >> 10) & 255];
        a.x += bv; a.y += bv; a.z += bv; a.w += bv;
    } else {
        float4 bv = *(const float4*)(bias + (flat & 255));
        a.x += bv.x; a.y += bv.y; a.z += bv.z; a.w += bv.w;
    }
    uint2 o = make_uint2(packh(a.x, a.y), packh(a.z, a.w));
    *(uint2*)(Out + flat) = o;
}

// ---------------------------------------------------------------------------
// Kernel 2 (R13/R14-proven): persistent-K/V fused attn, XCD-swizzled.
// ---------------------------------------------------------------------------
__global__ __launch_bounds__(512) void attn_mfma(
    const float* __restrict__ Qin, const u16* __restrict__ KpF,
    const u16* __restrict__ VpF,   u16* __restrict__ AO)
{
    const int lin = blockIdx.x + blockIdx.y * gridDim.x;
    const int tid = (lin & 7) * 32 + (lin >> 3);
    const int bh = tid >> 2, b = bh >> 4, h = bh & 15;
    const int n0 = (tid & 3) * 1024;
    const int t  = threadIdx.x;
    const int w    = t >> 6;          // wave 0..7
    const int lane = t & 63;
    const int q    = lane >> 4;       // quad 0..3
    const int c    = lane & 15;

    __shared__ u16 Kl[16384];         // K [256][64], chunk ^ (row&7)
    __shared__ u16 Vl[16384];         // V [64][256], low-3 chunk bits ^ (row&7)
    __shared__ u16 Pl[128 * 264];     // P / out bounce, wave-local rows

    const u16* kbase = KpF + (size_t)b * LK * DMODEL + h * DK;
#pragma unroll
    for (int i = 0; i < 4; ++i) {
        int li = i * 512 + t;
        int row = li >> 3, ch = li & 7;
        int chs = ch ^ (row & 7);
        gl2lds16(kbase + (size_t)row * DMODEL + chs * 8, Kl + (size_t)li * 8);
    }
    const u16* vbase = VpF + ((size_t)b * DMODEL + h * DK) * LK;
#pragma unroll
    for (int i = 0; i < 4; ++i) {
        int li = i * 512 + t;
        int row = li >> 5, ch = li & 31;
        int chs = (ch & 24) | ((ch & 7) ^ (row & 7));
        gl2lds16(vbase + (size_t)row * LK + chs * 8, Vl + (size_t)li * 8);
    }
    __syncthreads();   // ONLY barrier

    const float* qbase = Qin + ((size_t)b * SEQ + n0 + w * 16 + c) * DMODEL + h * DK;
    const float4* qp0 = (const float4*)qbase;
    float4 q0 = qp0[2 * q], q1 = qp0[2 * q + 1];
    float4 q2 = qp0[8 + 2 * q], q3 = qp0[8 + 2 * q + 1];

    for (int p = 0; p < 8; ++p) {
        f16x8 a0 = pack8h(q0, q1);
        f16x8 a1 = pack8h(q2, q3);
        if (p < 7) {
            const float4* qp = (const float4*)(qbase + (size_t)(p + 1) * 128 * DMODEL);
            q0 = qp[2 * q]; q1 = qp[2 * q + 1];
            q2 = qp[8 + 2 * q]; q3 = qp[8 + 2 * q + 1];
        }

        f32x4 sc[16];
#pragma unroll
        for (int nt = 0; nt < 16; ++nt) sc[nt] = (f32x4){0.f, 0.f, 0.f, 0.f};
#pragma unroll
        for (int nt = 0; nt < 16; ++nt) {
            int ra = (nt * 16 + c) * 64;
            f16x8 b0 = *(const f16x8*)&Kl[ra + ((q ^ (c & 7)) * 8)];
            f16x8 b1 = *(const f16x8*)&Kl[ra + (((4 + q) ^ (c & 7)) * 8)];
            sc[nt] = __builtin_amdgcn_mfma_f32_16x16x32_f16(a0, b0, sc[nt], 0, 0, 0);
            sc[nt] = __builtin_amdgcn_mfma_f32_16x16x32_f16(a1, b1, sc[nt], 0, 0, 0);
        }

        float mx[4] = {-1e30f, -1e30f, -1e30f, -1e30f};
#pragma unroll
        for (int nt = 0; nt < 16; ++nt) {
            sc[nt] *= 0.125f;   // 1/sqrt(DK)
#pragma unroll
            for (int r = 0; r < 4; ++r) mx[r] = fmaxf(mx[r], sc[nt][r]);
        }
#pragma unroll
        for (int d = 1; d < 16; d <<= 1)
#pragma unroll
            for (int r = 0; r < 4; ++r) mx[r] = fmaxf(mx[r], __shfl_xor(mx[r], d, 64));

        float sm[4] = {0.f, 0.f, 0.f, 0.f};
#pragma unroll
        for (int nt = 0; nt < 16; ++nt)
#pragma unroll
            for (int r = 0; r < 4; ++r) {
                float e = __expf(sc[nt][r] - mx[r]);
                sc[nt][r] = e;
                sm[r] += e;
            }
#pragma unroll
        for (int d = 1; d < 16; d <<= 1)
#pragma unroll
            for (int r = 0; r < 4; ++r) sm[r] += __shfl_xor(sm[r], d, 64);
        float inv[4];
#pragma unroll
        for (int r = 0; r < 4; ++r) inv[r] = 1.0f / sm[r];

#pragma unroll
        for (int nt = 0; nt < 16; ++nt)
#pragma unroll
            for (int r = 0; r < 4; ++r)
                Pl[(w * 16 + q * 4 + r) * 264 + nt * 16 + c] = f2h(sc[nt][r] * inv[r]);

        f32x4 ov[4];
#pragma unroll
        for (int nt = 0; nt < 4; ++nt) ov[nt] = (f32x4){0.f, 0.f, 0.f, 0.f};
#pragma unroll
        for (int ks = 0; ks < 8; ++ks) {
            f16x8 pa = *(const f16x8*)&Pl[(w * 16 + c) * 264 + ks * 32 + q * 8];
#pragma unroll
            for (int nt = 0; nt < 4; ++nt) {
                int chunk = ks * 4 + q;
                int chs = (chunk & 24) | ((chunk & 7) ^ (c & 7));
                f16x8 vf = *(const f16x8*)&Vl[(nt * 16 + c) * 256 + chs * 8];
                ov[nt] = __builtin_amdgcn_mfma_f32_16x16x32_f16(pa, vf, ov[nt], 0, 0, 0);
            }
        }

#pragma unroll
        for (int nt = 0; nt < 4; ++nt)
#pragma unroll
            for (int r = 0; r < 4; ++r)
                Pl[(w * 16 + q * 4 + r) * 264 + nt * 16 + c] = f2h(ov[nt][r]);

#pragma unroll
        for (int ps = 0; ps < 2; ++ps) {
            int lr  = w * 16 + ps * 8 + (lane >> 3);
            int col = (lane & 7) * 8;
            uint4 vv = *(uint4*)&Pl[lr * 264 + col];
            *(uint4*)(AO + ((size_t)b * SEQ + n0 + p * 128 + lr) * DMODEL + h * DK + col) = vv;
        }
    }
}

// ---------------------------------------------------------------------------
// Kernel 3 (R15): Out = AO(f16) @ WoT^T(f16) + bo, XCD-swizzled.
// Epilogue LDS-bounced: per-wave [16][68] f32 scratch (wave-local, no
// barrier), then coalesced float4 stores (256B segments).
// ---------------------------------------------------------------------------
#define OBM 128
#define OBN 128
#define OBK 64

__global__ __launch_bounds__(256) void out_gemm_mfma(
    const u16* __restrict__ AO, const u16* __restrict__ WoT,
    const float* __restrict__ bo, float* __restrict__ Out)
{
    const int lin = blockIdx.x + blockIdx.y * gridDim.x;   // 0..1023
    const int tid = (lin & 7) * 128 + (lin >> 3);
    const int r0 = (tid >> 3) * OBM;
    const int c0 = (tid & 7) * OBN;
    const int t  = threadIdx.x;
    const int lane = t & 63;
    const int w  = t >> 6;
    const int wr = w >> 1, wc = w & 1;
    const int q  = lane >> 4, c = lane & 15;

    __shared__ u16 As[OBM * OBK];
    __shared__ u16 Bs[OBN * OBK];
    __shared__ float Ol[4][16][68];   // per-wave epilogue bounce

    f32x4 acc[4][4];
#pragma unroll
    for (int m = 0; m < 4; ++m)
#pragma unroll
        for (int n = 0; n < 4; ++n) acc[m][n] = (f32x4){0.f, 0.f, 0.f, 0.f};

    for (int k0 = 0; k0 < DMODEL; k0 += OBK) {
#pragma unroll
        for (int i = 0; i < 4; ++i) {
            int li  = i * 256 + t;
            int row = li >> 3;
            int c8  = (li & 7) ^ (row & 7);
            gl2lds16(AO  + (size_t)(r0 + row) * DMODEL + k0 + c8 * 8, (u16*)As + (size_t)li * 8);
            gl2lds16(WoT + (size_t)(c0 + row) * DMODEL + k0 + c8 * 8, (u16*)Bs + (size_t)li * 8);
        }
        __syncthreads();

#pragma unroll
        for (int s = 0; s < 2; ++s) {
            f16x8 af[4], bf[4];
#pragma unroll
            for (int m = 0; m < 4; ++m) {
                int row = wr * 64 + m * 16 + c;
                int c8  = (s * 4 + q) ^ (row & 7);
                af[m] = *(const f16x8*)&As[row * 64 + c8 * 8];
            }
#pragma unroll
            for (int n = 0; n < 4; ++n) {
                int row = wc * 64 + n * 16 + c;
                int c8  = (s * 4 + q) ^ (row & 7);
                bf[n] = *(const f16x8*)&Bs[row * 64 + c8 * 8];
            }
#pragma unroll
            for (int m = 0; m < 4; ++m)
#pragma unroll
                for (int n = 0; n < 4; ++n)
                    acc[m][n] = __builtin_amdgcn_mfma_f32_16x16x32_f16(af[m], bf[n], acc[m][n], 0, 0, 0);
        }
        __syncthreads();
    }

    // epilogue: bias + wave-local LDS bounce -> coalesced float4 stores.
    float bv[4];
#pragma unroll
    for (int n = 0; n < 4; ++n) bv[n] = bo[c0 + wc * 64 + n * 16 + c];
#pragma unroll
    for (int m = 0; m < 4; ++m) {
#pragma unroll
        for (int r = 0; r < 4; ++r)
#pragma unroll
            for (int n = 0; n < 4; ++n)
                Ol[w][q * 4 + r][n * 16 + c] = acc[m][n][r] + bv[n];
        // wave-local: no barrier needed
#pragma unroll
        for (int i = 0; i < 4; ++i) {
            int rl = (lane >> 4) + i * 4;
            float4 v = *(const float4*)&Ol[w][rl][(lane & 15) * 4];
            float* dst = Out + (size_t)(r0 + wr * 64 + m * 16 + rl) * DMODEL
                       + c0 + wc * 64 + (lane & 15) * 4;
            *(float4*)dst = v;
        }
    }
}

// ---------------------------------------------------------------------------
extern "C" void kernel_launch(void* const* d_in, const int* in_sizes, int n_in,
                              void* d_out, int out_size, void* d_ws, size_t ws_size,
                              hipStream_t stream)
{
    const float* K   = (const float*)d_in[0];
    const float* Q   = (const float*)d_in[1];
    const float* V   = (const float*)d_in[2];
    const float* We  = (const float*)d_in[3];
    const float* be  = (const float*)d_in[4];
    const float* Wf  = (const float*)d_in[5];
    const float* bfp = (const float*)d_in[6];
    const float* Wo  = (const float*)d_in[7];
    const float* bo  = (const float*)d_in[8];
    float* Out = (float*)d_out;

    const size_t M1 = 1048576;                     // elems (2MB)
    const size_t TB = (size_t)BB * DMODEL * SEQ;   // elems (33.5MB)
    const size_t PFLOATS = (size_t)SPLITK * BB * LK * DMODEL;  // 4.19M floats
    const size_t NEED_SPLIT = (5 * M1 + 2 * TB) * 2 + 2 * PFLOATS * 4;  // ~111MB
    const size_t NEED_PAR   = 2 * (4 * M1 + 2 * TB);                     // ~75.5MB

    if (ws_size >= NEED_SPLIT) {
        // ---- R14/R15 split-K layout (~111MB) ----
        u16* KpF = (u16*)d_ws;
        u16* VpF = KpF + M1;
        u16* WeT = VpF + M1;
        u16* WfT = WeT + M1;
        u16* WoT = WfT + M1;
        u16* KT  = WoT + M1;
        u16* VT  = KT + TB;
        float* PPK = (float*)(VT + TB);
        float* PPV = PPK + PFLOATS;
        u16* AO  = KT;                   // alias: KT dead after proj

        tconv_all<<<dim3(4480), 256, 0, stream>>>(We, Wf, K, V, Wo, WeT, WfT, KT, VT, WoT);
        proj_split<<<dim3(128 * SPLITK), 256, 0, stream>>>(WeT, WfT, KT, VT, PPK, PPV);
        proj_reduce<<<dim3(1024, 2), 256, 0, stream>>>(PPK, PPV, be, bfp, KpF, VpF);
        attn_mfma<<<dim3(4, BH), 512, 0, stream>>>(Q, KpF, VpF, AO);
        out_gemm_mfma<<<dim3(DMODEL / OBN, (BB * SEQ) / OBM), 256, 0, stream>>>(AO, WoT, bo, Out);
    } else if (ws_size >= NEED_PAR) {
        // ---- R13 parallel layout (75.5MB, proven) ----
        u16* KpF = (u16*)d_ws;
        u16* VpF = KpF + M1;
        u16* WeT = VpF + M1;
        u16* WfT = WeT + M1;
        u16* KT  = WfT + M1;
        u16* VT  = KT + TB;
        u16* AO  = KT;
        u16* WoT = WeT;

        tconv<<<dim3(SEQ / 64, LK / 64, 1), 256, 0, stream>>>(We, WeT, LK, SEQ, 0, 0);
        tconv<<<dim3(SEQ / 64, LK / 64, 1), 256, 0, stream>>>(Wf, WfT, LK, SEQ, 0, 0);
        tconv<<<dim3(SEQ / 64, DMODEL / 64, BB), 256, 0, stream>>>(
            K, KT, DMODEL, SEQ, (size_t)SEQ * DMODEL, (size_t)DMODEL * SEQ);
        tconv<<<dim3(SEQ / 64, DMODEL / 64, BB), 256, 0, stream>>>(
            V, VT, DMODEL, SEQ, (size_t)SEQ * DMODEL, (size_t)DMODEL * SEQ);
        proj_both<<<dim3(128), 256, 0, stream>>>(WeT, WfT, KT, VT, be, bfp, KpF, VpF);
        wo_convert<<<dim3(DMODEL / 64, DMODEL / 64), 256, 0, stream>>>(Wo, WoT);
        attn_mfma<<<dim3(4, BH), 512, 0, stream>>>(Q, KpF, VpF, AO);
        out_gemm_mfma<<<dim3(DMODEL / OBN, (BB * SEQ) / OBM), 256, 0, stream>>>(AO, WoT, bo, Out);
    } else {
        // ---- serial fallback == exact R11 layout (39.5MB proven) ----
        u16* KpF = (u16*)d_ws;
        u16* VpF = KpF + (size_t)BB * LK * DMODEL;
        u16* BIG = VpF + (size_t)BB * DMODEL * LK;
        u16* Wsm = BIG + (size_t)BB * SEQ * DMODEL;

        tconv<<<dim3(SEQ / 64, LK / 64, 1), 256, 0, stream>>>(We, Wsm, LK, SEQ, 0, 0);
        tconv<<<dim3(SEQ / 64, DMODEL / 64, BB), 256, 0, stream>>>(
            K, BIG, DMODEL, SEQ, (size_t)SEQ * DMODEL, (size_t)DMODEL * SEQ);
        proj_gemm<<<dim3(DMODEL / 128, LK / 128, BB), 256, 0, stream>>>(
            Wsm, BIG, be, KpF, 1, (size_t)0, (size_t)DMODEL * SEQ, DMODEL, (size_t)LK * DMODEL);
        tconv<<<dim3(SEQ / 64, LK / 64, 1), 256, 0, stream>>>(Wf, Wsm, LK, SEQ, 0, 0);
        tconv<<<dim3(SEQ / 64, DMODEL / 64, BB), 256, 0, stream>>>(
            V, BIG, DMODEL, SEQ, (size_t)SEQ * DMODEL, (size_t)DMODEL * SEQ);
        proj_gemm<<<dim3(LK / 128, DMODEL / 128, BB), 256, 0, stream>>>(
            BIG, Wsm, bfp, VpF, 0, (size_t)DMODEL * SEQ, (size_t)0, LK, (size_t)DMODEL * LK);
        wo_convert<<<dim3(DMODEL / 64, DMODEL / 64), 256, 0, stream>>>(Wo, Wsm);
        attn_mfma<<<dim3(4, BH), 512, 0, stream>>>(Q, KpF, VpF, BIG);
        out_gemm_mfma<<<dim3(DMODEL / OBN, (BB * SEQ) / OBM), 256, 0, stream>>>(BIG, Wsm, bo, Out);
    }
}